// Round 1
// baseline (1988.497 us; speedup 1.0000x reference)
//
#include <hip/hip_runtime.h>
#include <cstdint>

typedef _Float16 f16;
typedef _Float16 f16x4v __attribute__((ext_vector_type(4)));
typedef _Float16 f16x8 __attribute__((ext_vector_type(8)));
typedef float f32x4 __attribute__((ext_vector_type(4)));

#define DEV static __device__ __forceinline__

// async global->LDS, 16B per lane; LDS dest = wave-uniform base + lane*16
#define GLDS16(gp, lp) __builtin_amdgcn_global_load_lds( \
    (const __attribute__((address_space(1))) void*)(gp), \
    (__attribute__((address_space(3))) void*)(lp), 16, 0, 0)

DEV float sigf(float x) { return 1.0f / (1.0f + __expf(-x)); }
DEV float tanh2(float x) {
  float e = __expf(-2.0f * fabsf(x));
  float t = (1.0f - e) / (1.0f + e);
  return x >= 0.0f ? t : -t;
}

// ---------------- fp32 -> fp16 convert (n % 4 == 0) ----------------
__global__ __launch_bounds__(256) void k_cvt(const float* __restrict__ s,
                                             f16* __restrict__ d, int n) {
  int i = (blockIdx.x * 256 + threadIdx.x) * 4;
  if (i >= n) return;
  float4 v = *(const float4*)(s + i);
  f16x4v o;
  o.x = (f16)v.x; o.y = (f16)v.y; o.z = (f16)v.z; o.w = (f16)v.w;
  *(f16x4v*)(d + i) = o;
}

// ---------------- pack Whh_1 (4096x1024 fp32) into MFMA fragment order -----
// layout: frag = (ut*4+gate)*32 + kt ; within frag: lane l holds 8 halves =
// W[gate*1024 + ut*16 + (l&15)][kt*32 + 8*(l>>4) + j]
__global__ __launch_bounds__(256) void k_packw1(const float* __restrict__ W,
                                                f16* __restrict__ P) {
  int i2 = blockIdx.x * 256 + threadIdx.x;   // 0 .. 524287
  int l = i2 & 63, frag = i2 >> 6;
  int kt = frag & 31, ug = frag >> 5;
  int gate = ug & 3, ut = ug >> 2;
  int row = gate * 1024 + ut * 16 + (l & 15);
  int k = kt * 32 + 8 * (l >> 4);
  const float* s = W + row * 1024 + k;
  f16x8 o;
#pragma unroll
  for (int j = 0; j < 8; ++j) o[j] = (f16)s[j];
  *(f16x8*)(P + frag * 512 + l * 8) = o;
}

// ---------------- pack [Wih_2 | Whh_2] (each 4096x1024) as K=2048 ----------
__global__ __launch_bounds__(256) void k_packw2(const float* __restrict__ Wih,
                                                const float* __restrict__ Whh,
                                                f16* __restrict__ P) {
  int i2 = blockIdx.x * 256 + threadIdx.x;   // 0 .. 1048575
  int l = i2 & 63, frag = i2 >> 6;           // frag 0..16383
  int kt = frag & 63, ug = frag >> 6;
  int gate = ug & 3, ut = ug >> 2;
  int row = gate * 1024 + ut * 16 + (l & 15);
  int k = kt * 32 + 8 * (l >> 4);
  const float* s = (k < 1024) ? (Wih + row * 1024 + k)
                              : (Whh + row * 1024 + (k - 1024));
  f16x8 o;
#pragma unroll
  for (int j = 0; j < 8; ++j) o[j] = (f16)s[j];
  *(f16x8*)(P + frag * 512 + l * 8) = o;
}

// ---------------- input GEMM: G0 = x16 @ Wih_1^T + (bih+bhh), fp16 out -----
// A (2048x2048), B (4096x2048) both row-major k-contiguous. 128x128 tile,
// BK=64, 4 waves each 64x64 (m97 structure, global_load_lds width 16).
__global__ __launch_bounds__(256) void k_igemm(
    const f16* __restrict__ A0, const f16* __restrict__ A1,
    const f16* __restrict__ B0, const f16* __restrict__ B1,
    const float* __restrict__ bi0, const float* __restrict__ bh0,
    const float* __restrict__ bi1, const float* __restrict__ bh1,
    f16* __restrict__ C0, f16* __restrict__ C1) {
  const f16* A = blockIdx.z ? A1 : A0;
  const f16* B = blockIdx.z ? B1 : B0;
  const float* bi = blockIdx.z ? bi1 : bi0;
  const float* bh = blockIdx.z ? bh1 : bh0;
  f16* C = blockIdx.z ? C1 : C0;

  __shared__ alignas(16) f16 As[128 * 64];
  __shared__ alignas(16) f16 Bs[128 * 64];

  int tid = threadIdx.x, l = tid & 63, w = tid >> 6;
  int m0 = blockIdx.x * 128, n0 = blockIdx.y * 128;
  int wm = (w & 1) * 64, wn = (w >> 1) * 64;
  int lr = l & 15, lg = l >> 4;
  int sr = w * 32 + (l >> 3);      // staging row (this lane)
  int sc = (l & 7) * 8;            // staging col in halves (16B chunks)

  f32x4 acc[4][4];
  f32x4 zero = {0.f, 0.f, 0.f, 0.f};
#pragma unroll
  for (int mt = 0; mt < 4; ++mt)
#pragma unroll
    for (int nt = 0; nt < 4; ++nt) acc[mt][nt] = zero;

  for (int kt = 0; kt < 32; ++kt) {
    int k0 = kt * 64;
#pragma unroll
    for (int c2 = 0; c2 < 4; ++c2) {
      GLDS16(A + (m0 + sr + c2 * 8) * 2048 + k0 + sc, &As[(w * 32 + c2 * 8) * 64]);
      GLDS16(B + (n0 + sr + c2 * 8) * 2048 + k0 + sc, &Bs[(w * 32 + c2 * 8) * 64]);
    }
    __syncthreads();
#pragma unroll
    for (int ks = 0; ks < 2; ++ks) {
      f16x8 af[4], bf[4];
#pragma unroll
      for (int mt = 0; mt < 4; ++mt)
        af[mt] = *(const f16x8*)&As[(wm + mt * 16 + lr) * 64 + ks * 32 + 8 * lg];
#pragma unroll
      for (int nt = 0; nt < 4; ++nt)
        bf[nt] = *(const f16x8*)&Bs[(wn + nt * 16 + lr) * 64 + ks * 32 + 8 * lg];
#pragma unroll
      for (int mt = 0; mt < 4; ++mt)
#pragma unroll
        for (int nt = 0; nt < 4; ++nt)
          acc[mt][nt] = __builtin_amdgcn_mfma_f32_16x16x32_f16(af[mt], bf[nt], acc[mt][nt], 0, 0, 0);
    }
    __syncthreads();
  }

#pragma unroll
  for (int nt = 0; nt < 4; ++nt) {
    int n = n0 + wn + nt * 16 + lr;
    float bsum = bi[n] + bh[n];
#pragma unroll
    for (int mt = 0; mt < 4; ++mt) {
      int m = m0 + wm + mt * 16 + lg * 4;
#pragma unroll
      for (int r = 0; r < 4; ++r)
        C[(m + r) * 4096 + n] = (f16)(acc[mt][nt][r] + bsum);
    }
  }
}

// ---------------- scan stage A: gates = G0[t] + h1_prev @ Whh_1^T ----------
// 128 blocks: s = bi>>6 (stream), ut = bi&63 (16 hidden units). 4 waves
// split K=1024 (256 each); LDS reduce; wave 0 does LSTM elementwise.
__global__ __launch_bounds__(256) void k_stageA(
    const f16* __restrict__ Wp_a, const f16* __restrict__ Wp_m,
    const f16* __restrict__ G0a, const f16* __restrict__ G0m,
    const f16* __restrict__ hP, f16* __restrict__ hC,
    float* __restrict__ c1, int t) {
  int bi = blockIdx.x;
  int s = bi >> 6, ut = bi & 63, u0 = ut * 16;
  const f16* Wp = s ? Wp_m : Wp_a;
  const f16* G0 = s ? G0m : G0a;
  const f16* hprev = hP + s * (32 * 2048);
  f16* hcur = hC + s * (32 * 2048);
  float* c = c1 + s * (32 * 1024);
  int tid = threadIdx.x, l = tid & 63, w = tid >> 6;
  int lr = l & 15, lg = l >> 4;

  f32x4 acc[2][4];
  f32x4 zero = {0.f, 0.f, 0.f, 0.f};
#pragma unroll
  for (int mt = 0; mt < 2; ++mt)
#pragma unroll
    for (int g = 0; g < 4; ++g) acc[mt][g] = zero;

#pragma unroll
  for (int ks = 0; ks < 8; ++ks) {
    int kk = w * 256 + ks * 32;
    f16x8 a0 = *(const f16x8*)(hprev + lr * 2048 + kk + 8 * lg);
    f16x8 a1 = *(const f16x8*)(hprev + (16 + lr) * 2048 + kk + 8 * lg);
#pragma unroll
    for (int g = 0; g < 4; ++g) {
      f16x8 b = *(const f16x8*)(Wp + ((ut * 4 + g) * 32 + (kk >> 5)) * 512 + l * 8);
      acc[0][g] = __builtin_amdgcn_mfma_f32_16x16x32_f16(a0, b, acc[0][g], 0, 0, 0);
      acc[1][g] = __builtin_amdgcn_mfma_f32_16x16x32_f16(a1, b, acc[1][g], 0, 0, 0);
    }
  }

  __shared__ float red[3][64][32];
  if (w) {
#pragma unroll
    for (int mt = 0; mt < 2; ++mt)
#pragma unroll
      for (int g = 0; g < 4; ++g)
#pragma unroll
        for (int r = 0; r < 4; ++r)
          red[w - 1][l][(mt * 4 + g) * 4 + r] = acc[mt][g][r];
  }
  __syncthreads();
  if (w == 0) {
#pragma unroll
    for (int mt = 0; mt < 2; ++mt)
#pragma unroll
      for (int g = 0; g < 4; ++g)
#pragma unroll
        for (int r = 0; r < 4; ++r) {
          int idx = (mt * 4 + g) * 4 + r;
          acc[mt][g][r] += red[0][l][idx] + red[1][l][idx] + red[2][l][idx];
        }
    int u = u0 + lr;
#pragma unroll
    for (int mt = 0; mt < 2; ++mt) {
#pragma unroll
      for (int r = 0; r < 4; ++r) {
        int b_ = mt * 16 + lg * 4 + r;
        int gb = (b_ * 64 + t) * 4096 + u;
        float pi = acc[mt][0][r] + (float)G0[gb];
        float pf = acc[mt][1][r] + (float)G0[gb + 1024];
        float pg = acc[mt][2][r] + (float)G0[gb + 2048];
        float po = acc[mt][3][r] + (float)G0[gb + 3072];
        float cn = sigf(pf) * c[b_ * 1024 + u] + sigf(pi) * tanh2(pg);
        c[b_ * 1024 + u] = cn;
        hcur[b_ * 2048 + u] = (f16)(sigf(po) * tanh2(cn));
      }
    }
  }
}

// ---------------- scan stage B: gates2 = [h1_cur ; h2_prev] @ W2cat^T + b2 -
__global__ __launch_bounds__(256) void k_stageB(
    const f16* __restrict__ Wp_a, const f16* __restrict__ Wp_m,
    const float* __restrict__ bi_a, const float* __restrict__ bh_a,
    const float* __restrict__ bi_m, const float* __restrict__ bh_m,
    const f16* __restrict__ hP, f16* __restrict__ hC,
    float* __restrict__ c2, f16* __restrict__ HaHm, int t) {
  int bi = blockIdx.x;
  int s = bi >> 6, ut = bi & 63, u0 = ut * 16;
  const f16* Wp = s ? Wp_m : Wp_a;
  const float* bip = s ? bi_m : bi_a;
  const float* bhp = s ? bh_m : bh_a;
  const f16* hp = hP + s * (32 * 2048);   // h2_prev lives in cols [1024,2048)
  f16* hc = hC + s * (32 * 2048);         // h1_cur in cols [0,1024); write h2 here
  float* c = c2 + s * (32 * 1024);
  int tid = threadIdx.x, l = tid & 63, w = tid >> 6;
  int lr = l & 15, lg = l >> 4;

  f32x4 acc[2][4];
  f32x4 zero = {0.f, 0.f, 0.f, 0.f};
#pragma unroll
  for (int mt = 0; mt < 2; ++mt)
#pragma unroll
    for (int g = 0; g < 4; ++g) acc[mt][g] = zero;

#pragma unroll
  for (int ks = 0; ks < 16; ++ks) {
    int kk = w * 512 + ks * 32;
    const f16* ha = (kk < 1024) ? hc : hp;  // k<1024: h1 (cur); else h2 (prev)
    f16x8 a0 = *(const f16x8*)(ha + lr * 2048 + kk + 8 * lg);
    f16x8 a1 = *(const f16x8*)(ha + (16 + lr) * 2048 + kk + 8 * lg);
#pragma unroll
    for (int g = 0; g < 4; ++g) {
      f16x8 b = *(const f16x8*)(Wp + ((ut * 4 + g) * 64 + (kk >> 5)) * 512 + l * 8);
      acc[0][g] = __builtin_amdgcn_mfma_f32_16x16x32_f16(a0, b, acc[0][g], 0, 0, 0);
      acc[1][g] = __builtin_amdgcn_mfma_f32_16x16x32_f16(a1, b, acc[1][g], 0, 0, 0);
    }
  }

  __shared__ float red[3][64][32];
  if (w) {
#pragma unroll
    for (int mt = 0; mt < 2; ++mt)
#pragma unroll
      for (int g = 0; g < 4; ++g)
#pragma unroll
        for (int r = 0; r < 4; ++r)
          red[w - 1][l][(mt * 4 + g) * 4 + r] = acc[mt][g][r];
  }
  __syncthreads();
  if (w == 0) {
#pragma unroll
    for (int mt = 0; mt < 2; ++mt)
#pragma unroll
      for (int g = 0; g < 4; ++g)
#pragma unroll
        for (int r = 0; r < 4; ++r) {
          int idx = (mt * 4 + g) * 4 + r;
          acc[mt][g][r] += red[0][l][idx] + red[1][l][idx] + red[2][l][idx];
        }
    int u = u0 + lr;
    float bs[4];
#pragma unroll
    for (int g = 0; g < 4; ++g) bs[g] = bip[g * 1024 + u] + bhp[g * 1024 + u];
#pragma unroll
    for (int mt = 0; mt < 2; ++mt) {
#pragma unroll
      for (int r = 0; r < 4; ++r) {
        int b_ = mt * 16 + lg * 4 + r;
        float pi = acc[mt][0][r] + bs[0];
        float pf = acc[mt][1][r] + bs[1];
        float pg = acc[mt][2][r] + bs[2];
        float po = acc[mt][3][r] + bs[3];
        float cn = sigf(pf) * c[b_ * 1024 + u] + sigf(pi) * tanh2(pg);
        c[b_ * 1024 + u] = cn;
        f16 h2 = (f16)(sigf(po) * tanh2(cn));
        hc[b_ * 2048 + 1024 + u] = h2;
        HaHm[(b_ * 64 + t) * 2048 + s * 1024 + u] = h2;
      }
    }
  }
}

// ---------------- fusion: one GEMM phase helper -----------------------------
DEV void gemm_phase(const f16* __restrict__ H, int kA0,
                    const f16* __restrict__ Bp, int brs, int nk,
                    f16* As, f16* Bs, int m0, int n0, int w, int l,
                    int wm, int wn, f32x4 (&acc)[4][2]) {
  f32x4 zero = {0.f, 0.f, 0.f, 0.f};
#pragma unroll
  for (int mt = 0; mt < 4; ++mt)
#pragma unroll
    for (int nt = 0; nt < 2; ++nt) acc[mt][nt] = zero;
  int lr = l & 15, lg = l >> 4;
  int sc = (l & 7) * 8;
  for (int kt = 0; kt < nk; ++kt) {
    int ka = kA0 + kt * 64, kb = kt * 64;
#pragma unroll
    for (int c2 = 0; c2 < 4; ++c2)
      GLDS16(H + (m0 + w * 32 + c2 * 8 + (l >> 3)) * 2048 + ka + sc,
             As + (w * 32 + c2 * 8) * 64);
#pragma unroll
    for (int c2 = 0; c2 < 2; ++c2)
      GLDS16(Bp + (n0 + w * 16 + c2 * 8 + (l >> 3)) * brs + kb + sc,
             Bs + (w * 16 + c2 * 8) * 64);
    __syncthreads();
#pragma unroll
    for (int ks = 0; ks < 2; ++ks) {
      f16x8 af[4], bf[2];
#pragma unroll
      for (int mt = 0; mt < 4; ++mt)
        af[mt] = *(const f16x8*)&As[(wm + mt * 16 + lr) * 64 + ks * 32 + 8 * lg];
#pragma unroll
      for (int nt = 0; nt < 2; ++nt)
        bf[nt] = *(const f16x8*)&Bs[(wn + nt * 16 + lr) * 64 + ks * 32 + 8 * lg];
#pragma unroll
      for (int mt = 0; mt < 4; ++mt)
#pragma unroll
        for (int nt = 0; nt < 2; ++nt)
          acc[mt][nt] = __builtin_amdgcn_mfma_f32_16x16x32_f16(af[mt], bf[nt], acc[mt][nt], 0, 0, 0);
    }
    __syncthreads();
  }
}

// mem = tm + sig(G)*(ta - tm); 128x64 tile per block, 4 waves of 64x32
__global__ __launch_bounds__(256) void k_fusion(
    const f16* __restrict__ H, const f16* __restrict__ Wg16,
    const f16* __restrict__ Wa16, const f16* __restrict__ Wm16,
    const float* __restrict__ bg, const float* __restrict__ ba,
    const float* __restrict__ bm, float* __restrict__ out) {
  __shared__ alignas(16) f16 As[128 * 64];
  __shared__ alignas(16) f16 Bs[64 * 64];
  int tid = threadIdx.x, l = tid & 63, w = tid >> 6;
  int m0 = blockIdx.x * 128, n0 = blockIdx.y * 64;
  int wm = (w & 1) * 64, wn = (w >> 1) * 32;
  int lr = l & 15, lg = l >> 4;

  f32x4 acc[4][2];
  float ta[4][2][4], tm[4][2][4];

  gemm_phase(H, 0, Wa16, 1024, 16, As, Bs, m0, n0, w, l, wm, wn, acc);
#pragma unroll
  for (int nt = 0; nt < 2; ++nt) {
    float bv = ba[n0 + wn + nt * 16 + lr];
#pragma unroll
    for (int mt = 0; mt < 4; ++mt)
#pragma unroll
      for (int r = 0; r < 4; ++r) ta[mt][nt][r] = tanh2(acc[mt][nt][r] + bv);
  }
  gemm_phase(H, 1024, Wm16, 1024, 16, As, Bs, m0, n0, w, l, wm, wn, acc);
#pragma unroll
  for (int nt = 0; nt < 2; ++nt) {
    float bv = bm[n0 + wn + nt * 16 + lr];
#pragma unroll
    for (int mt = 0; mt < 4; ++mt)
#pragma unroll
      for (int r = 0; r < 4; ++r) tm[mt][nt][r] = tanh2(acc[mt][nt][r] + bv);
  }
  gemm_phase(H, 0, Wg16, 2048, 32, As, Bs, m0, n0, w, l, wm, wn, acc);
#pragma unroll
  for (int nt = 0; nt < 2; ++nt) {
    int n = n0 + wn + nt * 16 + lr;
    float bv = bg[n];
#pragma unroll
    for (int mt = 0; mt < 4; ++mt) {
      int m = m0 + wm + mt * 16 + lg * 4;
#pragma unroll
      for (int r = 0; r < 4; ++r) {
        float g = sigf(acc[mt][nt][r] + bv);
        out[(m + r) * 1024 + n] = tm[mt][nt][r] + g * (ta[mt][nt][r] - tm[mt][nt][r]);
      }
    }
  }
}

// ===========================================================================
extern "C" void kernel_launch(void* const* d_in, const int* in_sizes, int n_in,
                              void* d_out, int out_size, void* d_ws, size_t ws_size,
                              hipStream_t stream) {
  const float* xa = (const float*)d_in[0];
  const float* xm = (const float*)d_in[1];
  const float* Wih_1a = (const float*)d_in[2];
  const float* Whh_1a = (const float*)d_in[3];
  const float* bih_1a = (const float*)d_in[4];
  const float* bhh_1a = (const float*)d_in[5];
  const float* Wih_2a = (const float*)d_in[6];
  const float* Whh_2a = (const float*)d_in[7];
  const float* bih_2a = (const float*)d_in[8];
  const float* bhh_2a = (const float*)d_in[9];
  const float* Wih_1m = (const float*)d_in[10];
  const float* Whh_1m = (const float*)d_in[11];
  const float* bih_1m = (const float*)d_in[12];
  const float* bhh_1m = (const float*)d_in[13];
  const float* Wih_2m = (const float*)d_in[14];
  const float* Whh_2m = (const float*)d_in[15];
  const float* bih_2m = (const float*)d_in[16];
  const float* bhh_2m = (const float*)d_in[17];
  const float* Wg = (const float*)d_in[18];
  const float* bg = (const float*)d_in[19];
  const float* Wa = (const float*)d_in[20];
  const float* ba = (const float*)d_in[21];
  const float* Wm = (const float*)d_in[22];
  const float* bm = (const float*)d_in[23];

  char* ws = (char*)d_ws;
  size_t off = 0;
  auto alloc = [&](size_t bytes) {
    char* p = ws + off;
    off += (bytes + 255) & ~(size_t)255;
    return p;
  };
  f16* x16a   = (f16*)alloc(2048ull * 2048 * 2);
  f16* x16m   = (f16*)alloc(2048ull * 2048 * 2);
  f16* W1ih16a = (f16*)alloc(4096ull * 2048 * 2);
  f16* W1ih16m = (f16*)alloc(4096ull * 2048 * 2);
  f16* W1p_a  = (f16*)alloc(4096ull * 1024 * 2);
  f16* W1p_m  = (f16*)alloc(4096ull * 1024 * 2);
  f16* W2p_a  = (f16*)alloc(4096ull * 2048 * 2);
  f16* W2p_m  = (f16*)alloc(4096ull * 2048 * 2);
  f16* Wg16   = (f16*)alloc(1024ull * 2048 * 2);
  f16* Wa16   = (f16*)alloc(1024ull * 1024 * 2);
  f16* Wm16   = (f16*)alloc(1024ull * 1024 * 2);
  f16* G0a    = (f16*)alloc(2048ull * 4096 * 2);
  f16* G0m    = (f16*)alloc(2048ull * 4096 * 2);
  f16* hbuf   = (f16*)alloc(2ull * 2 * 32 * 2048 * 2);  // ping-pong, both streams
  float* c1   = (float*)alloc(2ull * 32 * 1024 * 4);
  float* c2   = (float*)alloc(2ull * 32 * 1024 * 4);
  f16* HaHm   = (f16*)alloc(2048ull * 2048 * 2);
  if (off > ws_size) return;  // workspace too small: fail visibly (zeros)

  dim3 B256(256);
  k_cvt<<<4096, B256, 0, stream>>>(xa, x16a, 4194304);
  k_cvt<<<4096, B256, 0, stream>>>(xm, x16m, 4194304);
  k_cvt<<<8192, B256, 0, stream>>>(Wih_1a, W1ih16a, 8388608);
  k_cvt<<<8192, B256, 0, stream>>>(Wih_1m, W1ih16m, 8388608);
  k_cvt<<<2048, B256, 0, stream>>>(Wg, Wg16, 2097152);
  k_cvt<<<1024, B256, 0, stream>>>(Wa, Wa16, 1048576);
  k_cvt<<<1024, B256, 0, stream>>>(Wm, Wm16, 1048576);
  k_packw1<<<2048, B256, 0, stream>>>(Whh_1a, W1p_a);
  k_packw1<<<2048, B256, 0, stream>>>(Whh_1m, W1p_m);
  k_packw2<<<4096, B256, 0, stream>>>(Wih_2a, Whh_2a, W2p_a);
  k_packw2<<<4096, B256, 0, stream>>>(Wih_2m, Whh_2m, W2p_m);
  hipMemsetAsync(hbuf, 0, 2ull * 2 * 32 * 2048 * 2, stream);
  hipMemsetAsync(c1, 0, 2ull * 32 * 1024 * 4, stream);
  hipMemsetAsync(c2, 0, 2ull * 32 * 1024 * 4, stream);

  k_igemm<<<dim3(16, 32, 2), B256, 0, stream>>>(
      x16a, x16m, W1ih16a, W1ih16m, bih_1a, bhh_1a, bih_1m, bhh_1m, G0a, G0m);

  const size_t HB = 2ull * 32 * 2048;  // one ping-pong buffer (both streams)
  for (int t = 0; t < 64; ++t) {
    f16* P = hbuf + (size_t)(t & 1) * HB;
    f16* C = hbuf + (size_t)((t & 1) ^ 1) * HB;
    k_stageA<<<128, B256, 0, stream>>>(W1p_a, W1p_m, G0a, G0m, P, C, c1, t);
    k_stageB<<<128, B256, 0, stream>>>(W2p_a, W2p_m, bih_2a, bhh_2a, bih_2m,
                                       bhh_2m, P, C, c2, HaHm, t);
  }

  k_fusion<<<dim3(16, 16), B256, 0, stream>>>(HaHm, Wg16, Wa16, Wm16, bg, ba,
                                              bm, (float*)d_out);
}